// Round 1
// baseline (791.761 us; speedup 1.0000x reference)
//
#include <hip/hip_runtime.h>
#include <cstdint>

#define CONF_THRES 0.25f
#define IOU_THRES  0.45f
#define MAX_DET    300
#define K_TOP      8192
#define NA         102000
#define NCLS       80
#define ROWLEN     85
#define CAP        32768
#define NBUCKET    65536

typedef unsigned long long u64;
typedef unsigned int u32;

// ---------------- kernel 1: scores -> sortable keys + histogram ----------------
__global__ __launch_bounds__(256) void score_key_kernel(const float* __restrict__ preds,
        u64* __restrict__ keys, u32* __restrict__ hist) {
#pragma clang fp contract(off)
    int i = blockIdx.x * 256 + threadIdx.x;
    if (i >= NA) return;
    const float* p = preds + (size_t)i * ROWLEN;
    float obj = p[4];
    float best = p[5] * obj;
    for (int c = 1; c < NCLS; ++c) {
        float v = p[5 + c] * obj;
        if (v > best) best = v;
    }
    float score = (obj > CONF_THRES) ? best : 0.0f;
    u32 sb = __float_as_uint(score);           // score >= 0 -> bits are order-preserving
    keys[i] = ((u64)sb << 32) | (u32)(~(u32)i); // tie-break: smaller index = bigger key
    atomicAdd(&hist[sb >> 16], 1u);
}

// ---------------- kernel 2: find threshold bucket for top-K ----------------
__global__ __launch_bounds__(1024) void cutoff_kernel(const u32* __restrict__ hist,
        u32* __restrict__ meta) {
    __shared__ u32 chunk[1024];
    int t = threadIdx.x;
    u32 s = 0;
    for (int b = t * 64; b < t * 64 + 64; ++b) s += hist[b];
    chunk[t] = s;
    __syncthreads();
    if (t == 0) {
        u32 acc = 0;
        int cb = -1;
        for (int c = 1023; c >= 0; --c) {
            if (acc + chunk[c] >= (u32)K_TOP) { cb = c; break; }
            acc += chunk[c];
        }
        u32 thresh = 0;
        if (cb >= 0) {
            for (int b = cb * 64 + 63; b >= cb * 64; --b) {
                if (acc + hist[b] >= (u32)K_TOP) { thresh = (u32)b << 16; break; }
                acc += hist[b];
            }
        }
        meta[1] = thresh;   // meta[0] is the compact counter (zeroed by memset)
    }
}

// ---------------- kernel 3: compact candidates above threshold ----------------
__global__ __launch_bounds__(256) void compact_kernel(const u64* __restrict__ keys,
        u32* __restrict__ meta, u64* __restrict__ comp) {
    int i = blockIdx.x * 256 + threadIdx.x;
    if (i >= NA) return;
    u64 key = keys[i];
    if ((u32)(key >> 32) >= meta[1]) {
        u32 pos = atomicAdd(&meta[0], 1u);
        if (pos < CAP) comp[pos] = key;
    }
}

// ---------------- kernel 4: rank-by-counting -> sorted top-K keys ----------------
__global__ __launch_bounds__(256) void rank_kernel(const u64* __restrict__ comp,
        const u32* __restrict__ meta, u64* __restrict__ sorted) {
    __shared__ u64 tile[1024];
    int tid = blockIdx.x * 256 + threadIdx.x;
    u32 cnt = meta[0];
    int n = (int)(cnt < (u32)CAP ? cnt : (u32)CAP);
    u64 key = (tid < n) ? comp[tid] : 0ull;
    u32 rank = 0;
    for (int base = 0; base < n; base += 1024) {
        int lim = (n - base < 1024) ? (n - base) : 1024;
        __syncthreads();
        for (int k = threadIdx.x; k < lim; k += 256) tile[k] = comp[base + k];
        __syncthreads();
        if (tid < n) {
            for (int j = 0; j < lim; ++j) rank += (tile[j] > key) ? 1u : 0u;
        }
    }
    if (tid < n && rank < (u32)K_TOP) sorted[rank] = key;  // keys unique -> perm
}

// ---------------- kernel 5: gather boxes/classes/scores for top-K ----------------
__global__ __launch_bounds__(256) void gather_kernel(const u64* __restrict__ sorted,
        const float* __restrict__ preds, float* __restrict__ boxes,
        float* __restrict__ scores, float* __restrict__ classes) {
#pragma clang fp contract(off)
    int i = blockIdx.x * 256 + threadIdx.x;
    u64 key = sorted[i];
    u32 sb = (u32)(key >> 32);
    float score = __uint_as_float(sb);
    if (score > 0.0f) {
        u32 idx = ~(u32)(key & 0xffffffffull);
        const float* p = preds + (size_t)idx * ROWLEN;
        float x = p[0], y = p[1], w = p[2], h = p[3], obj = p[4];
        float best = p[5] * obj; int bc = 0;
        for (int c = 1; c < NCLS; ++c) {
            float v = p[5 + c] * obj;
            if (v > best) { best = v; bc = c; }
        }
        boxes[i * 4 + 0] = y - h * 0.5f;   // ymin
        boxes[i * 4 + 1] = x - w * 0.5f;   // xmin
        boxes[i * 4 + 2] = y + h * 0.5f;   // ymax
        boxes[i * 4 + 3] = x + w * 0.5f;   // xmax
        scores[i] = score;
        classes[i] = (float)bc;
    } else {
        boxes[i * 4 + 0] = 0.0f; boxes[i * 4 + 1] = 0.0f;
        boxes[i * 4 + 2] = 0.0f; boxes[i * 4 + 3] = 0.0f;
        scores[i] = 0.0f;
        classes[i] = 0.0f;
    }
}

// ---------------- kernel 6: suppression bitmask (iou > thres, j > i) ----------------
__global__ __launch_bounds__(256) void mask_kernel(const float* __restrict__ boxes,
        u64* __restrict__ mask) {
#pragma clang fp contract(off)
    __shared__ float4 cb[64];
    int wj = blockIdx.x;                 // column word 0..127
    int i = blockIdx.y * 256 + threadIdx.x;
    int j0 = wj * 64;
    if (threadIdx.x < 64) cb[threadIdx.x] = ((const float4*)boxes)[j0 + threadIdx.x];
    __syncthreads();
    float4 bi = ((const float4*)boxes)[i];
    float area_i = (bi.z - bi.x) * (bi.w - bi.y);
    u64 bits = 0;
    if (j0 + 63 > i) {
        for (int k = 0; k < 64; ++k) {
            int j = j0 + k;
            if (j <= i) continue;
            float4 bj = cb[k];
            float area_j = (bj.z - bj.x) * (bj.w - bj.y);
            float ty = fmaxf(bi.x, bj.x);
            float tx = fmaxf(bi.y, bj.y);
            float by = fminf(bi.z, bj.z);
            float bx = fminf(bi.w, bj.w);
            float inter = fmaxf(by - ty, 0.0f) * fmaxf(bx - tx, 0.0f);
            float uni = (area_i + area_j) - inter;
            float iou = inter / (uni + 1e-9f);
            if (iou > IOU_THRES) bits |= (1ull << k);
        }
    }
    mask[(size_t)i * 128 + wj] = bits;
}

// ---------------- kernel 7: single-wave sequential greedy scan + output ----------------
__global__ __launch_bounds__(64) void nms_scan_kernel(const u64* __restrict__ mask,
        const float* __restrict__ boxes, const float* __restrict__ scores,
        const float* __restrict__ classes, float* __restrict__ out) {
    int lane = threadIdx.x;              // exactly one wave
    // lane owns bitset words `lane` (rem0) and `lane+64` (rem1): 8192 bits total
    u64 rem0 = 0, rem1 = 0;
    for (int w = 0; w < 128; ++w) {
        u64 b = __ballot(scores[w * 64 + lane] > 0.0f);
        if (w == lane) rem0 = b;
        if (w - 64 == lane) rem1 = b;
    }
    int n = 0;
    while (n < MAX_DET) {
        // lowest remaining index
        u64 nz0 = __ballot(rem0 != 0ull);
        int i;
        if (nz0 != 0ull) {
            int w = __ffsll((unsigned long long)nz0) - 1;
            u64 word = __shfl(rem0, w);
            i = w * 64 + (__ffsll((unsigned long long)word) - 1);
        } else {
            u64 nz1 = __ballot(rem1 != 0ull);
            if (nz1 == 0ull) break;
            int w = __ffsll((unsigned long long)nz1) - 1;
            u64 word = __shfl(rem1, w);
            i = (w + 64) * 64 + (__ffsll((unsigned long long)word) - 1);
        }
        // keep i: it is the n-th detection (top_scores already sorted descending)
        if (lane < 4) out[n * 4 + lane] = boxes[i * 4 + lane];
        if (lane == 0) { out[1200 + n] = classes[i]; out[1500 + n] = scores[i]; }
        ++n;
        // suppress row i and clear bit i
        const u64* row = mask + (size_t)i * 128;
        rem0 &= ~row[lane];
        rem1 &= ~row[lane + 64];
        int wi = i >> 6;
        if (wi < 64) { if (lane == wi) rem0 &= ~(1ull << (i & 63)); }
        else         { if (lane == wi - 64) rem1 &= ~(1ull << (i & 63)); }
    }
    // zero-fill the remaining slots (harness poisons d_out with 0xAA)
    for (int m = n; m < MAX_DET; ++m) {
        if (lane < 4) out[m * 4 + lane] = 0.0f;
        if (lane == 0) { out[1200 + m] = 0.0f; out[1500 + m] = 0.0f; }
    }
}

// ---------------- launch ----------------
extern "C" void kernel_launch(void* const* d_in, const int* in_sizes, int n_in,
                              void* d_out, int out_size, void* d_ws, size_t ws_size,
                              hipStream_t stream) {
    const float* preds = (const float*)d_in[0];
    char* ws = (char*)d_ws;

    // ws layout (bytes):
    //   [0, 262144)            hist        u32[65536]
    //   [262144, 262400)       meta        u32[64]   ([0]=counter, [1]=thresh)
    //   [262400, 327936)       sorted      u64[8192]
    //   [327936, 1143936)      keys        u64[102000]
    //   [1143936, 1406080)     comp        u64[32768]
    //   [1406080, 1537152)     top_boxes   f32[8192*4]
    //   [1537152, 1569920)     top_scores  f32[8192]
    //   [1569920, 1602688)     top_classes f32[8192]
    //   [1602688, 9991296)     mask        u64[8192*128]   (8 MB)
    u32*   hist    = (u32*)(ws + 0);
    u32*   meta    = (u32*)(ws + 262144);
    u64*   sorted  = (u64*)(ws + 262400);
    u64*   keys    = (u64*)(ws + 327936);
    u64*   comp    = (u64*)(ws + 1143936);
    float* tboxes  = (float*)(ws + 1406080);
    float* tscores = (float*)(ws + 1537152);
    float* tclass  = (float*)(ws + 1569920);
    u64*   mask    = (u64*)(ws + 1602688);
    float* out     = (float*)d_out;

    // zero hist + meta + sorted in one shot
    hipMemsetAsync(ws, 0, 327936, stream);

    score_key_kernel<<<(NA + 255) / 256, 256, 0, stream>>>(preds, keys, hist);
    cutoff_kernel<<<1, 1024, 0, stream>>>(hist, meta);
    compact_kernel<<<(NA + 255) / 256, 256, 0, stream>>>(keys, meta, comp);
    rank_kernel<<<CAP / 256, 256, 0, stream>>>(comp, meta, sorted);
    gather_kernel<<<K_TOP / 256, 256, 0, stream>>>(sorted, preds, tboxes, tscores, tclass);
    mask_kernel<<<dim3(128, K_TOP / 256), 256, 0, stream>>>(tboxes, mask);
    nms_scan_kernel<<<1, 64, 0, stream>>>(mask, tboxes, tscores, tclass, out);
}

// Round 2
// 782.844 us; speedup vs baseline: 1.0114x; 1.0114x over previous
//
#include <hip/hip_runtime.h>
#include <cstdint>

#define CONF_THRES 0.25f
#define IOU_THRES  0.45f
#define MAX_DET    300
#define K_TOP      8192
#define NA         102000
#define NCLS       80
#define ROWLEN     85
#define CAP        32768
#define NBUCKET    65536

typedef unsigned long long u64;
typedef unsigned int u32;

// ---------------- kernel 1: wave-per-anchor scores -> sortable keys + histogram ----
// Lane l reads row[l] and row[64+l]: fully coalesced (340B/row). Max over classes via
// shfl_xor reduction. round(max_c v_c * obj) == max_c round(v_c*obj) (monotone mul).
__global__ __launch_bounds__(256) void score_key_kernel(const float* __restrict__ preds,
        u64* __restrict__ keys, u32* __restrict__ hist) {
#pragma clang fp contract(off)
    int lane = threadIdx.x & 63;
    int i = blockIdx.x * 4 + (threadIdx.x >> 6);     // 4 waves/block, 1 anchor/wave
    if (i >= NA) return;
    const float* p = preds + (size_t)i * ROWLEN;
    float v0 = p[lane];                               // offsets 0..63
    float v1 = (lane < ROWLEN - 64) ? p[64 + lane] : 0.0f; // offsets 64..84
    float obj = __shfl(v0, 4);
    float m = (lane >= 5) ? v0 : 0.0f;                // classes 0..58 (scores >= 0)
    m = fmaxf(m, (lane < 21) ? v1 : 0.0f);            // classes 59..79
    for (int off = 32; off; off >>= 1) m = fmaxf(m, __shfl_xor(m, off));
    if (lane == 0) {
        float score = (obj > CONF_THRES) ? m * obj : 0.0f;
        u32 sb = __float_as_uint(score);              // score >= 0: order-preserving bits
        keys[i] = ((u64)sb << 32) | (u32)(~(u32)i);   // tie-break: smaller index wins
        atomicAdd(&hist[sb >> 16], 1u);
    }
}

// ---------------- kernel 2: find threshold bucket for top-K ----------------
__global__ __launch_bounds__(1024) void cutoff_kernel(const u32* __restrict__ hist,
        u32* __restrict__ meta) {
    __shared__ u32 chunk[1024];
    int t = threadIdx.x;
    u32 s = 0;
    for (int b = t * 64; b < t * 64 + 64; ++b) s += hist[b];
    chunk[t] = s;
    __syncthreads();
    if (t == 0) {
        u32 acc = 0;
        int cb = -1;
        for (int c = 1023; c >= 0; --c) {
            if (acc + chunk[c] >= (u32)K_TOP) { cb = c; break; }
            acc += chunk[c];
        }
        u32 thresh = 0;
        if (cb >= 0) {
            for (int b = cb * 64 + 63; b >= cb * 64; --b) {
                if (acc + hist[b] >= (u32)K_TOP) { thresh = (u32)b << 16; break; }
                acc += hist[b];
            }
        }
        meta[1] = thresh;   // meta[0] is the compact counter (zeroed by memset)
    }
}

// ---------------- kernel 3: compact candidates above threshold ----------------
__global__ __launch_bounds__(256) void compact_kernel(const u64* __restrict__ keys,
        u32* __restrict__ meta, u64* __restrict__ comp) {
    int i = blockIdx.x * 256 + threadIdx.x;
    if (i >= NA) return;
    u64 key = keys[i];
    if ((u32)(key >> 32) >= meta[1]) {
        u32 pos = atomicAdd(&meta[0], 1u);
        if (pos < CAP) comp[pos] = key;
    }
}

// ---------------- kernel 4: rank-by-counting -> sorted top-K keys ----------------
__global__ __launch_bounds__(256) void rank_kernel(const u64* __restrict__ comp,
        const u32* __restrict__ meta, u64* __restrict__ sorted) {
    __shared__ u64 tile[1024];
    u32 cnt = meta[0];
    int n = (int)(cnt < (u32)CAP ? cnt : (u32)CAP);
    if (blockIdx.x * 256 >= n) return;               // whole-block early exit (uniform)
    int tid = blockIdx.x * 256 + threadIdx.x;
    u64 key = (tid < n) ? comp[tid] : 0ull;
    u32 rank = 0;
    for (int base = 0; base < n; base += 1024) {
        int lim = (n - base < 1024) ? (n - base) : 1024;
        __syncthreads();
        for (int k = threadIdx.x; k < lim; k += 256) tile[k] = comp[base + k];
        __syncthreads();
        if (tid < n) {
            for (int j = 0; j < lim; ++j) rank += (tile[j] > key) ? 1u : 0u;
        }
    }
    if (tid < n && rank < (u32)K_TOP) sorted[rank] = key;  // keys unique -> perm
}

// ---------------- kernel 5: wave-per-anchor gather of boxes/classes/scores ---------
__global__ __launch_bounds__(256) void gather_kernel(const u64* __restrict__ sorted,
        const float* __restrict__ preds, float* __restrict__ boxes,
        float* __restrict__ scores, float* __restrict__ classes) {
#pragma clang fp contract(off)
    int lane = threadIdx.x & 63;
    int i = blockIdx.x * 4 + (threadIdx.x >> 6);     // i in [0, 8192)
    u64 key = sorted[i];
    u32 sb = (u32)(key >> 32);
    float score = __uint_as_float(sb);
    if (score > 0.0f) {                               // uniform across the wave
        u32 idx = ~(u32)(key & 0xffffffffull);
        const float* p = preds + (size_t)idx * ROWLEN;
        float v0 = p[lane];
        float v1 = (lane < ROWLEN - 64) ? p[64 + lane] : 0.0f;
        float obj = __shfl(v0, 4);
        // argmax over products, first-index tie-break: key=(bits<<8)|(255-cls), max
        u64 kb = 0;
        if (lane >= 5) {
            float q = v0 * obj;                       // class lane-5
            kb = ((u64)__float_as_uint(q) << 8) | (u32)(255 - (lane - 5));
        }
        if (lane < 21) {
            float q = v1 * obj;                       // class 59+lane
            u64 kb2 = ((u64)__float_as_uint(q) << 8) | (u32)(255 - (59 + lane));
            if (kb2 > kb) kb = kb2;
        }
        for (int off = 32; off; off >>= 1) {
            u64 o = __shfl_xor(kb, off);
            if (o > kb) kb = o;
        }
        u32 cls = 255u - (u32)(kb & 0xffull);
        float x = __shfl(v0, 0), y = __shfl(v0, 1);
        float w = __shfl(v0, 2), h = __shfl(v0, 3);
        if (lane == 0) {
            boxes[i * 4 + 0] = y - h * 0.5f;          // ymin
            boxes[i * 4 + 1] = x - w * 0.5f;          // xmin
            boxes[i * 4 + 2] = y + h * 0.5f;          // ymax
            boxes[i * 4 + 3] = x + w * 0.5f;          // xmax
            scores[i] = score;
            classes[i] = (float)cls;
        }
    } else if (lane == 0) {
        boxes[i * 4 + 0] = 0.0f; boxes[i * 4 + 1] = 0.0f;
        boxes[i * 4 + 2] = 0.0f; boxes[i * 4 + 3] = 0.0f;
        scores[i] = 0.0f;
        classes[i] = 0.0f;
    }
}

// ---------------- kernel 6: suppression bitmask (iou > thres, j > i) ----------------
__global__ __launch_bounds__(256) void mask_kernel(const float* __restrict__ boxes,
        u64* __restrict__ mask) {
#pragma clang fp contract(off)
    __shared__ float4 cb[64];
    int wj = blockIdx.x;                 // column word 0..127
    int i = blockIdx.y * 256 + threadIdx.x;
    int j0 = wj * 64;
    if (threadIdx.x < 64) cb[threadIdx.x] = ((const float4*)boxes)[j0 + threadIdx.x];
    __syncthreads();
    float4 bi = ((const float4*)boxes)[i];
    float area_i = (bi.z - bi.x) * (bi.w - bi.y);
    u64 bits = 0;
    if (j0 + 63 > i) {
        for (int k = 0; k < 64; ++k) {
            int j = j0 + k;
            if (j <= i) continue;
            float4 bj = cb[k];
            float area_j = (bj.z - bj.x) * (bj.w - bj.y);
            float ty = fmaxf(bi.x, bj.x);
            float tx = fmaxf(bi.y, bj.y);
            float by = fminf(bi.z, bj.z);
            float bx = fminf(bi.w, bj.w);
            float inter = fmaxf(by - ty, 0.0f) * fmaxf(bx - tx, 0.0f);
            float uni = (area_i + area_j) - inter;
            float iou = inter / (uni + 1e-9f);
            if (iou > IOU_THRES) bits |= (1ull << k);
        }
    }
    mask[(size_t)i * 128 + wj] = bits;
}

// ---------------- kernel 7: single-wave sequential greedy scan + output ----------------
__global__ __launch_bounds__(64) void nms_scan_kernel(const u64* __restrict__ mask,
        const float* __restrict__ boxes, const float* __restrict__ scores,
        const float* __restrict__ classes, float* __restrict__ out) {
    int lane = threadIdx.x;              // exactly one wave
    // lane owns bitset words `lane` (rem0) and `lane+64` (rem1): 8192 bits total
    u64 rem0 = 0, rem1 = 0;
    for (int w = 0; w < 128; ++w) {
        u64 b = __ballot(scores[w * 64 + lane] > 0.0f);
        if (w == lane) rem0 = b;
        if (w - 64 == lane) rem1 = b;
    }
    int n = 0;
    while (n < MAX_DET) {
        // lowest remaining index
        u64 nz0 = __ballot(rem0 != 0ull);
        int i;
        if (nz0 != 0ull) {
            int w = __ffsll((unsigned long long)nz0) - 1;
            u64 word = __shfl(rem0, w);
            i = w * 64 + (__ffsll((unsigned long long)word) - 1);
        } else {
            u64 nz1 = __ballot(rem1 != 0ull);
            if (nz1 == 0ull) break;
            int w = __ffsll((unsigned long long)nz1) - 1;
            u64 word = __shfl(rem1, w);
            i = (w + 64) * 64 + (__ffsll((unsigned long long)word) - 1);
        }
        // keep i: it is the n-th detection (top_scores already sorted descending)
        if (lane < 4) out[n * 4 + lane] = boxes[i * 4 + lane];
        if (lane == 0) { out[1200 + n] = classes[i]; out[1500 + n] = scores[i]; }
        ++n;
        // suppress row i and clear bit i
        const u64* row = mask + (size_t)i * 128;
        rem0 &= ~row[lane];
        rem1 &= ~row[lane + 64];
        int wi = i >> 6;
        if (wi < 64) { if (lane == wi) rem0 &= ~(1ull << (i & 63)); }
        else         { if (lane == wi - 64) rem1 &= ~(1ull << (i & 63)); }
    }
    // zero-fill the remaining slots (harness poisons d_out with 0xAA)
    for (int m = n; m < MAX_DET; ++m) {
        if (lane < 4) out[m * 4 + lane] = 0.0f;
        if (lane == 0) { out[1200 + m] = 0.0f; out[1500 + m] = 0.0f; }
    }
}

// ---------------- launch ----------------
extern "C" void kernel_launch(void* const* d_in, const int* in_sizes, int n_in,
                              void* d_out, int out_size, void* d_ws, size_t ws_size,
                              hipStream_t stream) {
    const float* preds = (const float*)d_in[0];
    char* ws = (char*)d_ws;

    // ws layout (bytes):
    //   [0, 262144)            hist        u32[65536]
    //   [262144, 262400)       meta        u32[64]   ([0]=counter, [1]=thresh)
    //   [262400, 327936)       sorted      u64[8192]
    //   [327936, 1143936)      keys        u64[102000]
    //   [1143936, 1406080)     comp        u64[32768]
    //   [1406080, 1537152)     top_boxes   f32[8192*4]
    //   [1537152, 1569920)     top_scores  f32[8192]
    //   [1569920, 1602688)     top_classes f32[8192]
    //   [1602688, 9991296)     mask        u64[8192*128]   (8 MB)
    u32*   hist    = (u32*)(ws + 0);
    u32*   meta    = (u32*)(ws + 262144);
    u64*   sorted  = (u64*)(ws + 262400);
    u64*   keys    = (u64*)(ws + 327936);
    u64*   comp    = (u64*)(ws + 1143936);
    float* tboxes  = (float*)(ws + 1406080);
    float* tscores = (float*)(ws + 1537152);
    float* tclass  = (float*)(ws + 1569920);
    u64*   mask    = (u64*)(ws + 1602688);
    float* out     = (float*)d_out;

    // zero hist + meta + sorted in one shot
    hipMemsetAsync(ws, 0, 327936, stream);

    score_key_kernel<<<(NA + 3) / 4, 256, 0, stream>>>(preds, keys, hist);
    cutoff_kernel<<<1, 1024, 0, stream>>>(hist, meta);
    compact_kernel<<<(NA + 255) / 256, 256, 0, stream>>>(keys, meta, comp);
    rank_kernel<<<CAP / 256, 256, 0, stream>>>(comp, meta, sorted);
    gather_kernel<<<K_TOP / 4, 256, 0, stream>>>(sorted, preds, tboxes, tscores, tclass);
    mask_kernel<<<dim3(128, K_TOP / 256), 256, 0, stream>>>(tboxes, mask);
    nms_scan_kernel<<<1, 64, 0, stream>>>(mask, tboxes, tscores, tclass, out);
}

// Round 3
// 652.896 us; speedup vs baseline: 1.2127x; 1.1990x over previous
//
#include <hip/hip_runtime.h>
#include <cstdint>

#define CONF_THRES 0.25f
#define IOU_THRES  0.45f
#define MAX_DET    300
#define K_TOP      8192
#define NA         102000
#define NCLS       80
#define ROWLEN     85
#define CAP        32768
#define NBUCKET    65536

typedef unsigned long long u64;
typedef unsigned int u32;

// ---------------- kernel 1: wave-per-anchor scores -> sortable keys + histogram ----
// Lane l reads row[l] and row[64+l]: fully coalesced (340B/row). Max over classes via
// shfl_xor reduction. round(max_c v_c * obj) == max_c round(v_c*obj) (monotone mul).
// sb==0 entries are NOT histogrammed: ~25% of anchors have obj<=0.25 and all of them
// would serialize on hist[0] (same-address L2 atomics ~10ns each = ~250us). cutoff's
// result is unchanged: zero bucket only matters when positives < K, where thresh=0
// either way.
__global__ __launch_bounds__(256) void score_key_kernel(const float* __restrict__ preds,
        u64* __restrict__ keys, u32* __restrict__ hist) {
#pragma clang fp contract(off)
    int lane = threadIdx.x & 63;
    int i = blockIdx.x * 4 + (threadIdx.x >> 6);     // 4 waves/block, 1 anchor/wave
    if (i >= NA) return;
    const float* p = preds + (size_t)i * ROWLEN;
    float v0 = p[lane];                               // offsets 0..63
    float v1 = (lane < ROWLEN - 64) ? p[64 + lane] : 0.0f; // offsets 64..84
    float obj = __shfl(v0, 4);
    float m = (lane >= 5) ? v0 : 0.0f;                // classes 0..58 (scores >= 0)
    m = fmaxf(m, (lane < 21) ? v1 : 0.0f);            // classes 59..79
    for (int off = 32; off; off >>= 1) m = fmaxf(m, __shfl_xor(m, off));
    if (lane == 0) {
        float score = (obj > CONF_THRES) ? m * obj : 0.0f;
        u32 sb = __float_as_uint(score);              // score >= 0: order-preserving bits
        keys[i] = ((u64)sb << 32) | (u32)(~(u32)i);   // tie-break: smaller index wins
        if (sb != 0u) atomicAdd(&hist[sb >> 16], 1u);
    }
}

// ---------------- kernel 2: find threshold bucket for top-K ----------------
__global__ __launch_bounds__(1024) void cutoff_kernel(const u32* __restrict__ hist,
        u32* __restrict__ meta) {
    __shared__ u32 chunk[1024];
    int t = threadIdx.x;
    u32 s = 0;
    for (int b = t * 64; b < t * 64 + 64; ++b) s += hist[b];
    chunk[t] = s;
    __syncthreads();
    if (t == 0) {
        u32 acc = 0;
        int cb = -1;
        for (int c = 1023; c >= 0; --c) {
            if (acc + chunk[c] >= (u32)K_TOP) { cb = c; break; }
            acc += chunk[c];
        }
        u32 thresh = 0;
        if (cb >= 0) {
            for (int b = cb * 64 + 63; b >= cb * 64; --b) {
                if (acc + hist[b] >= (u32)K_TOP) { thresh = (u32)b << 16; break; }
                acc += hist[b];
            }
        }
        meta[1] = thresh;   // meta[0] is the compact counter (zeroed by memset)
    }
}

// ---------------- kernel 3: compact candidates above threshold ----------------
// Block-aggregated counter: one atomicAdd per 256-thread block instead of one
// wave-coalesced atomic per wave (~1600 serialized same-address atomics -> ~400).
__global__ __launch_bounds__(256) void compact_kernel(const u64* __restrict__ keys,
        u32* __restrict__ meta, u64* __restrict__ comp) {
    __shared__ u32 woff[4];
    __shared__ u32 bbase;
    int i = blockIdx.x * 256 + threadIdx.x;
    int wid = threadIdx.x >> 6, lane = threadIdx.x & 63;
    u64 key = (i < NA) ? keys[i] : 0ull;
    u32 sb = (u32)(key >> 32);
    u32 th = meta[1];
    // sb!=0 guard: when th==0 (fewer than K positives) zeros must not flood comp[];
    // zeros are never emitted by the reference either (valid = score > 0).
    bool take = (i < NA) && (sb != 0u) && (sb >= th);
    u64 bal = __ballot(take);
    if (lane == 0) woff[wid] = (u32)__popcll(bal);
    __syncthreads();
    if (threadIdx.x == 0) {
        u32 t0 = woff[0], t1 = woff[1], t2 = woff[2], t3 = woff[3];
        bbase = atomicAdd(&meta[0], t0 + t1 + t2 + t3);
        woff[0] = 0; woff[1] = t0; woff[2] = t0 + t1; woff[3] = t0 + t1 + t2;
    }
    __syncthreads();
    if (take) {
        u32 pos = bbase + woff[wid] + (u32)__popcll(bal & ((1ull << lane) - 1ull));
        if (pos < CAP) comp[pos] = key;
    }
}

// ---------------- kernel 4: rank-by-counting -> sorted top-K keys ----------------
__global__ __launch_bounds__(256) void rank_kernel(const u64* __restrict__ comp,
        const u32* __restrict__ meta, u64* __restrict__ sorted) {
    __shared__ u64 tile[1024];
    u32 cnt = meta[0];
    int n = (int)(cnt < (u32)CAP ? cnt : (u32)CAP);
    if (blockIdx.x * 256 >= n) return;               // whole-block early exit (uniform)
    int tid = blockIdx.x * 256 + threadIdx.x;
    u64 key = (tid < n) ? comp[tid] : 0ull;
    u32 rank = 0;
    for (int base = 0; base < n; base += 1024) {
        int lim = (n - base < 1024) ? (n - base) : 1024;
        __syncthreads();
        for (int k = threadIdx.x; k < lim; k += 256) tile[k] = comp[base + k];
        __syncthreads();
        if (tid < n) {
            for (int j = 0; j < lim; ++j) rank += (tile[j] > key) ? 1u : 0u;
        }
    }
    if (tid < n && rank < (u32)K_TOP) sorted[rank] = key;  // keys unique -> perm
}

// ---------------- kernel 5: wave-per-anchor gather of boxes/classes/scores ---------
__global__ __launch_bounds__(256) void gather_kernel(const u64* __restrict__ sorted,
        const float* __restrict__ preds, float* __restrict__ boxes,
        float* __restrict__ scores, float* __restrict__ classes) {
#pragma clang fp contract(off)
    int lane = threadIdx.x & 63;
    int i = blockIdx.x * 4 + (threadIdx.x >> 6);     // i in [0, 8192)
    u64 key = sorted[i];
    u32 sb = (u32)(key >> 32);
    float score = __uint_as_float(sb);
    if (score > 0.0f) {                               // uniform across the wave
        u32 idx = ~(u32)(key & 0xffffffffull);
        const float* p = preds + (size_t)idx * ROWLEN;
        float v0 = p[lane];
        float v1 = (lane < ROWLEN - 64) ? p[64 + lane] : 0.0f;
        float obj = __shfl(v0, 4);
        // argmax over products, first-index tie-break: key=(bits<<8)|(255-cls), max
        u64 kb = 0;
        if (lane >= 5) {
            float q = v0 * obj;                       // class lane-5
            kb = ((u64)__float_as_uint(q) << 8) | (u32)(255 - (lane - 5));
        }
        if (lane < 21) {
            float q = v1 * obj;                       // class 59+lane
            u64 kb2 = ((u64)__float_as_uint(q) << 8) | (u32)(255 - (59 + lane));
            if (kb2 > kb) kb = kb2;
        }
        for (int off = 32; off; off >>= 1) {
            u64 o = __shfl_xor(kb, off);
            if (o > kb) kb = o;
        }
        u32 cls = 255u - (u32)(kb & 0xffull);
        float x = __shfl(v0, 0), y = __shfl(v0, 1);
        float w = __shfl(v0, 2), h = __shfl(v0, 3);
        if (lane == 0) {
            boxes[i * 4 + 0] = y - h * 0.5f;          // ymin
            boxes[i * 4 + 1] = x - w * 0.5f;          // xmin
            boxes[i * 4 + 2] = y + h * 0.5f;          // ymax
            boxes[i * 4 + 3] = x + w * 0.5f;          // xmax
            scores[i] = score;
            classes[i] = (float)cls;
        }
    } else if (lane == 0) {
        boxes[i * 4 + 0] = 0.0f; boxes[i * 4 + 1] = 0.0f;
        boxes[i * 4 + 2] = 0.0f; boxes[i * 4 + 3] = 0.0f;
        scores[i] = 0.0f;
        classes[i] = 0.0f;
    }
}

// ---------------- kernel 6: suppression bitmask (iou > thres, j > i) ----------------
__global__ __launch_bounds__(256) void mask_kernel(const float* __restrict__ boxes,
        u64* __restrict__ mask) {
#pragma clang fp contract(off)
    __shared__ float4 cb[64];
    int wj = blockIdx.x;                 // column word 0..127
    int i = blockIdx.y * 256 + threadIdx.x;
    int j0 = wj * 64;
    if (threadIdx.x < 64) cb[threadIdx.x] = ((const float4*)boxes)[j0 + threadIdx.x];
    __syncthreads();
    float4 bi = ((const float4*)boxes)[i];
    float area_i = (bi.z - bi.x) * (bi.w - bi.y);
    u64 bits = 0;
    if (j0 + 63 > i) {
        for (int k = 0; k < 64; ++k) {
            int j = j0 + k;
            if (j <= i) continue;
            float4 bj = cb[k];
            float area_j = (bj.z - bj.x) * (bj.w - bj.y);
            float ty = fmaxf(bi.x, bj.x);
            float tx = fmaxf(bi.y, bj.y);
            float by = fminf(bi.z, bj.z);
            float bx = fminf(bi.w, bj.w);
            float inter = fmaxf(by - ty, 0.0f) * fmaxf(bx - tx, 0.0f);
            float uni = (area_i + area_j) - inter;
            float iou = inter / (uni + 1e-9f);
            if (iou > IOU_THRES) bits |= (1ull << k);
        }
    }
    mask[(size_t)i * 128 + wj] = bits;
}

// ---------------- kernel 7: single-wave sequential greedy scan + output ----------------
__device__ __forceinline__ int find_first_idx(u64 w0, u64 w1) {
    u64 nz0 = __ballot(w0 != 0ull);
    if (nz0 != 0ull) {
        int w = __ffsll((unsigned long long)nz0) - 1;
        u64 word = __shfl(w0, w);
        return w * 64 + __ffsll((unsigned long long)word) - 1;
    }
    u64 nz1 = __ballot(w1 != 0ull);
    if (nz1 != 0ull) {
        int w = __ffsll((unsigned long long)nz1) - 1;
        u64 word = __shfl(w1, w);
        return (w + 64) * 64 + __ffsll((unsigned long long)word) - 1;
    }
    return -1;
}

__global__ __launch_bounds__(64) void nms_scan_kernel(const u64* __restrict__ mask,
        const float* __restrict__ boxes, const float* __restrict__ scores,
        const float* __restrict__ classes, float* __restrict__ out) {
    int lane = threadIdx.x;              // exactly one wave
    // lane owns bitset words `lane` (rem0) and `lane+64` (rem1): 8192 bits total
    u64 rem0 = 0, rem1 = 0;
    for (int w = 0; w < 128; ++w) {
        u64 b = __ballot(scores[w * 64 + lane] > 0.0f);
        if (w == lane) rem0 = b;
        if (w - 64 == lane) rem1 = b;
    }
    int n = 0;
    int ip = -1;                          // predicted next index with prefetched row
    u64 pre0 = 0, pre1 = 0;
    while (n < MAX_DET) {
        int i = find_first_idx(rem0, rem1);
        if (i < 0) break;
        // row for i: prefetched last iteration if prediction hit
        u64 r0, r1;
        if (i == ip) {
            r0 = pre0; r1 = pre1;
        } else {
            const u64* row = mask + (size_t)i * 128;
            r0 = row[lane]; r1 = row[lane + 64];
        }
        // clear bit i -> t0/t1; speculate next kept = next set bit (pre row-i apply)
        u64 t0 = rem0, t1 = rem1;
        {
            int wi = i >> 6;
            u64 bit = 1ull << (i & 63);
            if (wi < 64) { if (lane == wi) t0 &= ~bit; }
            else         { if (lane == wi - 64) t1 &= ~bit; }
        }
        int i2 = find_first_idx(t0, t1);
        if (i2 >= 0) {
            const u64* prow = mask + (size_t)i2 * 128;
            pre0 = prow[lane]; pre1 = prow[lane + 64];   // issued early, used next iter
            ip = i2;
        } else {
            ip = -1;
        }
        // emit detection n = i (top list already sorted by score desc)
        if (lane < 4) out[n * 4 + lane] = boxes[i * 4 + lane];
        if (lane == 0) { out[1200 + n] = classes[i]; out[1500 + n] = scores[i]; }
        ++n;
        // apply suppression row i
        rem0 = t0 & ~r0;
        rem1 = t1 & ~r1;
    }
    // zero-fill the remaining slots (harness poisons d_out with 0xAA)
    for (int m = n; m < MAX_DET; ++m) {
        if (lane < 4) out[m * 4 + lane] = 0.0f;
        if (lane == 0) { out[1200 + m] = 0.0f; out[1500 + m] = 0.0f; }
    }
}

// ---------------- launch ----------------
extern "C" void kernel_launch(void* const* d_in, const int* in_sizes, int n_in,
                              void* d_out, int out_size, void* d_ws, size_t ws_size,
                              hipStream_t stream) {
    const float* preds = (const float*)d_in[0];
    char* ws = (char*)d_ws;

    // ws layout (bytes):
    //   [0, 262144)            hist        u32[65536]
    //   [262144, 262400)       meta        u32[64]   ([0]=counter, [1]=thresh)
    //   [262400, 327936)       sorted      u64[8192]
    //   [327936, 1143936)      keys        u64[102000]
    //   [1143936, 1406080)     comp        u64[32768]
    //   [1406080, 1537152)     top_boxes   f32[8192*4]
    //   [1537152, 1569920)     top_scores  f32[8192]
    //   [1569920, 1602688)     top_classes f32[8192]
    //   [1602688, 9991296)     mask        u64[8192*128]   (8 MB)
    u32*   hist    = (u32*)(ws + 0);
    u32*   meta    = (u32*)(ws + 262144);
    u64*   sorted  = (u64*)(ws + 262400);
    u64*   keys    = (u64*)(ws + 327936);
    u64*   comp    = (u64*)(ws + 1143936);
    float* tboxes  = (float*)(ws + 1406080);
    float* tscores = (float*)(ws + 1537152);
    float* tclass  = (float*)(ws + 1569920);
    u64*   mask    = (u64*)(ws + 1602688);
    float* out     = (float*)d_out;

    // zero hist + meta + sorted in one shot
    hipMemsetAsync(ws, 0, 327936, stream);

    score_key_kernel<<<(NA + 3) / 4, 256, 0, stream>>>(preds, keys, hist);
    cutoff_kernel<<<1, 1024, 0, stream>>>(hist, meta);
    compact_kernel<<<(NA + 255) / 256, 256, 0, stream>>>(keys, meta, comp);
    rank_kernel<<<CAP / 256, 256, 0, stream>>>(comp, meta, sorted);
    gather_kernel<<<K_TOP / 4, 256, 0, stream>>>(sorted, preds, tboxes, tscores, tclass);
    mask_kernel<<<dim3(128, K_TOP / 256), 256, 0, stream>>>(tboxes, mask);
    nms_scan_kernel<<<1, 64, 0, stream>>>(mask, tboxes, tscores, tclass, out);
}

// Round 4
// 615.896 us; speedup vs baseline: 1.2855x; 1.0601x over previous
//
#include <hip/hip_runtime.h>
#include <cstdint>

#define CONF_THRES 0.25f
#define IOU_THRES  0.45f
#define MAX_DET    300
#define K_TOP      8192
#define NA         102000
#define NCLS       80
#define ROWLEN     85
#define CAP        32640
#define NPLANE     32
#define DQ         8

typedef unsigned long long u64;
typedef unsigned int u32;

// ---------------- kernel 1: wave-per-anchor scores -> sortable keys + histogram ----
// Histogram goes to 32 replicated planes (plane = blockIdx&31, plane-major layout) to
// cut same-line L2 atomic serialization ~32x. Planes live in the mask region (free
// space: mask_kernel overwrites it only after cutoff consumed the histogram).
__global__ __launch_bounds__(256) void score_key_kernel(const float* __restrict__ preds,
        u64* __restrict__ keys, u32* __restrict__ histP) {
#pragma clang fp contract(off)
    int lane = threadIdx.x & 63;
    int i = blockIdx.x * 4 + (threadIdx.x >> 6);     // 4 waves/block, 1 anchor/wave
    if (i >= NA) return;
    const float* p = preds + (size_t)i * ROWLEN;
    float v0 = p[lane];                               // offsets 0..63
    float v1 = (lane < ROWLEN - 64) ? p[64 + lane] : 0.0f; // offsets 64..84
    float obj = __shfl(v0, 4);
    float m = (lane >= 5) ? v0 : 0.0f;                // classes 0..58 (scores >= 0)
    m = fmaxf(m, (lane < 21) ? v1 : 0.0f);            // classes 59..79
    for (int off = 32; off; off >>= 1) m = fmaxf(m, __shfl_xor(m, off));
    if (lane == 0) {
        float score = (obj > CONF_THRES) ? m * obj : 0.0f;
        u32 sb = __float_as_uint(score);              // score >= 0: order-preserving bits
        keys[i] = ((u64)sb << 32) | (u32)(~(u32)i);   // tie-break: smaller index wins
        if (sb != 0u)
            atomicAdd(&histP[((u32)blockIdx.x & (NPLANE - 1u)) * 65536u + (sb >> 16)], 1u);
    }
}

// ---------------- kernel 1b: fold 32 histogram planes -> sumhist ----------------
__global__ __launch_bounds__(256) void reduce_hist_kernel(const u32* __restrict__ histP,
        u32* __restrict__ sumhist) {
    int bin = blockIdx.x * 256 + threadIdx.x;         // grid 256 -> 65536 bins
    u32 s = 0;
#pragma unroll
    for (int r = 0; r < NPLANE; ++r) s += histP[r * 65536 + bin];
    sumhist[bin] = s;
}

// ---------------- kernel 2: find threshold bucket for top-K ----------------
__global__ __launch_bounds__(1024) void cutoff_kernel(const u32* __restrict__ hist,
        u32* __restrict__ meta) {
    __shared__ u32 chunk[1024];
    int t = threadIdx.x;
    u32 s = 0;
    for (int b = t * 64; b < t * 64 + 64; ++b) s += hist[b];
    chunk[t] = s;
    __syncthreads();
    if (t == 0) {
        u32 acc = 0;
        int cb = -1;
        for (int c = 1023; c >= 0; --c) {
            if (acc + chunk[c] >= (u32)K_TOP) { cb = c; break; }
            acc += chunk[c];
        }
        u32 thresh = 0;
        if (cb >= 0) {
            for (int b = cb * 64 + 63; b >= cb * 64; --b) {
                if (acc + hist[b] >= (u32)K_TOP) { thresh = (u32)b << 16; break; }
                acc += hist[b];
            }
        }
        meta[1] = thresh;   // meta[0] is the compact counter (zeroed by memset)
    }
}

// ---------------- kernel 3: compact candidates above threshold ----------------
__global__ __launch_bounds__(256) void compact_kernel(const u64* __restrict__ keys,
        u32* __restrict__ meta, u64* __restrict__ comp) {
    __shared__ u32 woff[4];
    __shared__ u32 bbase;
    int i = blockIdx.x * 256 + threadIdx.x;
    int wid = threadIdx.x >> 6, lane = threadIdx.x & 63;
    u64 key = (i < NA) ? keys[i] : 0ull;
    u32 sb = (u32)(key >> 32);
    u32 th = meta[1];
    bool take = (i < NA) && (sb != 0u) && (sb >= th);
    u64 bal = __ballot(take);
    if (lane == 0) woff[wid] = (u32)__popcll(bal);
    __syncthreads();
    if (threadIdx.x == 0) {
        u32 t0 = woff[0], t1 = woff[1], t2 = woff[2], t3 = woff[3];
        bbase = atomicAdd(&meta[0], t0 + t1 + t2 + t3);
        woff[0] = 0; woff[1] = t0; woff[2] = t0 + t1; woff[3] = t0 + t1 + t2;
    }
    __syncthreads();
    if (take) {
        u32 pos = bbase + woff[wid] + (u32)__popcll(bal & ((1ull << lane) - 1ull));
        if (pos < CAP) comp[pos] = key;
    }
}

// ---------------- kernel 4: rank-by-counting -> sorted top-K keys ----------------
__global__ __launch_bounds__(256) void rank_kernel(const u64* __restrict__ comp,
        const u32* __restrict__ meta, u64* __restrict__ sorted) {
    __shared__ u64 tile[1024];
    u32 cnt = meta[0];
    int n = (int)(cnt < (u32)CAP ? cnt : (u32)CAP);
    if (blockIdx.x * 256 >= n) return;               // whole-block early exit (uniform)
    int tid = blockIdx.x * 256 + threadIdx.x;
    u64 key = (tid < n) ? comp[tid] : 0ull;
    u32 rank = 0;
    for (int base = 0; base < n; base += 1024) {
        int lim = (n - base < 1024) ? (n - base) : 1024;
        __syncthreads();
        for (int k = threadIdx.x; k < lim; k += 256) tile[k] = comp[base + k];
        __syncthreads();
        if (tid < n) {
            for (int j = 0; j < lim; ++j) rank += (tile[j] > key) ? 1u : 0u;
        }
    }
    if (tid < n && rank < (u32)K_TOP) sorted[rank] = key;  // keys unique -> perm
}

// ---------------- kernel 5: wave-per-anchor gather of boxes/classes/scores ---------
__global__ __launch_bounds__(256) void gather_kernel(const u64* __restrict__ sorted,
        const float* __restrict__ preds, float* __restrict__ boxes,
        float* __restrict__ scores, float* __restrict__ classes) {
#pragma clang fp contract(off)
    int lane = threadIdx.x & 63;
    int i = blockIdx.x * 4 + (threadIdx.x >> 6);     // i in [0, 8192)
    u64 key = sorted[i];
    u32 sb = (u32)(key >> 32);
    float score = __uint_as_float(sb);
    if (score > 0.0f) {                               // uniform across the wave
        u32 idx = ~(u32)(key & 0xffffffffull);
        const float* p = preds + (size_t)idx * ROWLEN;
        float v0 = p[lane];
        float v1 = (lane < ROWLEN - 64) ? p[64 + lane] : 0.0f;
        float obj = __shfl(v0, 4);
        // argmax over products, first-index tie-break: key=(bits<<8)|(255-cls), max
        u64 kb = 0;
        if (lane >= 5) {
            float q = v0 * obj;                       // class lane-5
            kb = ((u64)__float_as_uint(q) << 8) | (u32)(255 - (lane - 5));
        }
        if (lane < 21) {
            float q = v1 * obj;                       // class 59+lane
            u64 kb2 = ((u64)__float_as_uint(q) << 8) | (u32)(255 - (59 + lane));
            if (kb2 > kb) kb = kb2;
        }
        for (int off = 32; off; off >>= 1) {
            u64 o = __shfl_xor(kb, off);
            if (o > kb) kb = o;
        }
        u32 cls = 255u - (u32)(kb & 0xffull);
        float x = __shfl(v0, 0), y = __shfl(v0, 1);
        float w = __shfl(v0, 2), h = __shfl(v0, 3);
        if (lane == 0) {
            boxes[i * 4 + 0] = y - h * 0.5f;          // ymin
            boxes[i * 4 + 1] = x - w * 0.5f;          // xmin
            boxes[i * 4 + 2] = y + h * 0.5f;          // ymax
            boxes[i * 4 + 3] = x + w * 0.5f;          // xmax
            scores[i] = score;
            classes[i] = (float)cls;
        }
    } else if (lane == 0) {
        boxes[i * 4 + 0] = 0.0f; boxes[i * 4 + 1] = 0.0f;
        boxes[i * 4 + 2] = 0.0f; boxes[i * 4 + 3] = 0.0f;
        scores[i] = 0.0f;
        classes[i] = 0.0f;
    }
}

// ---------------- kernel 6: suppression bitmask (iou > thres, j > i) ----------------
__global__ __launch_bounds__(256) void mask_kernel(const float* __restrict__ boxes,
        u64* __restrict__ mask) {
#pragma clang fp contract(off)
    __shared__ float4 cb[64];
    int wj = blockIdx.x;                 // column word 0..127
    int i = blockIdx.y * 256 + threadIdx.x;
    int j0 = wj * 64;
    if (threadIdx.x < 64) cb[threadIdx.x] = ((const float4*)boxes)[j0 + threadIdx.x];
    __syncthreads();
    float4 bi = ((const float4*)boxes)[i];
    float area_i = (bi.z - bi.x) * (bi.w - bi.y);
    u64 bits = 0;
    if (j0 + 63 > i) {
        for (int k = 0; k < 64; ++k) {
            int j = j0 + k;
            if (j <= i) continue;
            float4 bj = cb[k];
            float area_j = (bj.z - bj.x) * (bj.w - bj.y);
            float ty = fmaxf(bi.x, bj.x);
            float tx = fmaxf(bi.y, bj.y);
            float by = fminf(bi.z, bj.z);
            float bx = fminf(bi.w, bj.w);
            float inter = fmaxf(by - ty, 0.0f) * fmaxf(bx - tx, 0.0f);
            float uni = (area_i + area_j) - inter;
            float iou = inter / (uni + 1e-9f);
            if (iou > IOU_THRES) bits |= (1ull << k);
        }
    }
    mask[(size_t)i * 128 + wj] = bits;
}

// ---------------- kernel 6b: validity words (rem init) for the scan ----------------
__global__ __launch_bounds__(256) void valid_kernel(const float* __restrict__ scores,
        u64* __restrict__ remw) {
    int w = blockIdx.x * 4 + (threadIdx.x >> 6);      // 128 waves over 32 blocks
    int lane = threadIdx.x & 63;
    u64 b = __ballot(scores[w * 64 + lane] > 0.0f);
    if (lane == 0) remw[w] = b;
}

// ---------------- kernel 7: single-wave greedy scan, depth-8 row prefetch ----------
__device__ __forceinline__ u64 bcast64(u64 v, int srclane) {
    u32 lo = (u32)__builtin_amdgcn_readlane((int)(u32)v, srclane);
    u32 hi = (u32)__builtin_amdgcn_readlane((int)(u32)(v >> 32), srclane);
    return ((u64)hi << 32) | lo;
}

__device__ __forceinline__ int ffidx(u64 w0, u64 w1) {
    u64 nz0 = __ballot(w0 != 0ull);
    if (nz0 != 0ull) {
        int w = __ffsll((unsigned long long)nz0) - 1;
        u64 word = bcast64(w0, w);
        return w * 64 + __ffsll((unsigned long long)word) - 1;
    }
    u64 nz1 = __ballot(w1 != 0ull);
    if (nz1 != 0ull) {
        int w = __ffsll((unsigned long long)nz1) - 1;
        u64 word = bcast64(w1, w);
        return (w + 64) * 64 + __ffsll((unsigned long long)word) - 1;
    }
    return -1;
}

__global__ __launch_bounds__(64) void nms_scan_kernel(const u64* __restrict__ mask,
        const u64* __restrict__ remw, const float* __restrict__ boxes,
        const float* __restrict__ scores, const float* __restrict__ classes,
        float* __restrict__ out) {
    int lane = threadIdx.x;              // exactly one wave
    u64 rem0 = remw[lane], rem1 = remw[64 + lane];
    // Speculation set: superset of rem in index order (only popped bits removed,
    // suppression never applied) -> queue always holds the next DQ candidate
    // indices in ascending order, rows prefetched DQ steps ahead.
    u64 sp0 = rem0, sp1 = rem1;
    int qi[DQ];
    u64 q0[DQ], q1[DQ];
#pragma unroll
    for (int d = 0; d < DQ; ++d) {
        int t = ffidx(sp0, sp1);
        qi[d] = t; q0[d] = 0; q1[d] = 0;
        if (t >= 0) {
            int wi = t >> 6; u64 bit = 1ull << (t & 63);
            if (wi < 64) { if (lane == wi) sp0 &= ~bit; }
            else         { if (lane == wi - 64) sp1 &= ~bit; }
            const u64* row = mask + (size_t)t * 128;
            q0[d] = row[lane]; q1[d] = row[lane + 64];
        }
    }
    int n = 0;
    bool work = true;
    while (work && n < MAX_DET) {
        work = false;
#pragma unroll
        for (int d = 0; d < DQ; ++d) {
            int i = qi[d];
            u64 r0 = q0[d], r1 = q1[d];
            // refill slot d with the next speculative candidate (load has DQ steps
            // of slack before its first use)
            int t = ffidx(sp0, sp1);
            qi[d] = t; q0[d] = 0; q1[d] = 0;
            if (t >= 0) {
                int wt = t >> 6; u64 bt = 1ull << (t & 63);
                if (wt < 64) { if (lane == wt) sp0 &= ~bt; }
                else         { if (lane == wt - 64) sp1 &= ~bt; }
                const u64* row = mask + (size_t)t * 128;
                q0[d] = row[lane]; q1[d] = row[lane + 64];
            }
            if (i >= 0) {
                work = true;
                int wi = i >> 6; u64 bit = 1ull << (i & 63);
                bool mine = (wi < 64) ? ((lane == wi) && (rem0 & bit))
                                      : ((lane == wi - 64) && (rem1 & bit));
                bool alive = (__ballot(mine) != 0ull);
                if (alive && n < MAX_DET) {
                    if (lane < 4) out[n * 4 + lane] = boxes[i * 4 + lane];
                    if (lane == 0) { out[1200 + n] = classes[i]; out[1500 + n] = scores[i]; }
                    ++n;
                    rem0 &= ~r0; rem1 &= ~r1;
                    if (wi < 64) { if (lane == wi) rem0 &= ~bit; }
                    else         { if (lane == wi - 64) rem1 &= ~bit; }
                }
            }
        }
    }
    // zero-fill the remaining slots (harness poisons d_out with 0xAA)
    for (int m = n; m < MAX_DET; ++m) {
        if (lane < 4) out[m * 4 + lane] = 0.0f;
        if (lane == 0) { out[1200 + m] = 0.0f; out[1500 + m] = 0.0f; }
    }
}

// ---------------- launch ----------------
extern "C" void kernel_launch(void* const* d_in, const int* in_sizes, int n_in,
                              void* d_out, int out_size, void* d_ws, size_t ws_size,
                              hipStream_t stream) {
    const float* preds = (const float*)d_in[0];
    char* ws = (char*)d_ws;

    // ws layout (bytes), total 9991104 (<= round-1's proven 9991296):
    //   [0, 262144)            sumhist     u32[65536]
    //   [262144, 262208)       meta        u32[16]   ([0]=counter, [1]=thresh)
    //   [262208, 263232)       remw        u64[128]
    //   [263232, 328768)       sorted      u64[8192]
    //   [328768, 1144768)      keys        u64[102000]
    //   [1144768, 1405888)     comp        u64[32640]
    //   [1405888, 1536960)     top_boxes   f32[8192*4]
    //   [1536960, 1569728)     top_scores  f32[8192]
    //   [1569728, 1602496)     top_classes f32[8192]
    //   [1602496, 9991104)     mask        u64[8192*128]  (8 MB; doubles as the
    //                                      32-plane histogram before mask_kernel)
    u32*   sumhist = (u32*)(ws + 0);
    u32*   meta    = (u32*)(ws + 262144);
    u64*   remw    = (u64*)(ws + 262208);
    u64*   sorted  = (u64*)(ws + 263232);
    u64*   keys    = (u64*)(ws + 328768);
    u64*   comp    = (u64*)(ws + 1144768);
    float* tboxes  = (float*)(ws + 1405888);
    float* tscores = (float*)(ws + 1536960);
    float* tclass  = (float*)(ws + 1569728);
    u64*   mask    = (u64*)(ws + 1602496);
    u32*   histP   = (u32*)(ws + 1602496);           // aliases mask region
    float* out     = (float*)d_out;

    hipMemsetAsync(ws, 0, 328768, stream);           // sumhist+meta+remw+sorted
    hipMemsetAsync(histP, 0, (size_t)NPLANE * 65536 * 4, stream);  // hist planes (8 MB)

    score_key_kernel<<<(NA + 3) / 4, 256, 0, stream>>>(preds, keys, histP);
    reduce_hist_kernel<<<256, 256, 0, stream>>>(histP, sumhist);
    cutoff_kernel<<<1, 1024, 0, stream>>>(sumhist, meta);
    compact_kernel<<<(NA + 255) / 256, 256, 0, stream>>>(keys, meta, comp);
    rank_kernel<<<(CAP + 255) / 256, 256, 0, stream>>>(comp, meta, sorted);
    gather_kernel<<<K_TOP / 4, 256, 0, stream>>>(sorted, preds, tboxes, tscores, tclass);
    mask_kernel<<<dim3(128, K_TOP / 256), 256, 0, stream>>>(tboxes, mask);
    valid_kernel<<<32, 256, 0, stream>>>(tscores, remw);
    nms_scan_kernel<<<1, 64, 0, stream>>>(mask, remw, tboxes, tscores, tclass, out);
}